// Round 5
// baseline (1756.566 us; speedup 1.0000x reference)
//
#include <hip/hip_runtime.h>
#include <math.h>

#define R1C 16384

enum { OP_STORE = 0, OP_SILU = 1, OP_RESID = 2, OP_TR = 3 };

typedef _Float16 f16x8 __attribute__((ext_vector_type(8)));
typedef float f32x4 __attribute__((ext_vector_type(4)));

__device__ __forceinline__ float silu_f(float x) { return x / (1.0f + __expf(-x)); }
__device__ __forceinline__ float gelu_f(float x) {
  return 0.5f * x * (1.0f + erff(x * 0.70710678118654752f));
}

__device__ __forceinline__ void gll16(const void* g, const void* l) {
  __builtin_amdgcn_global_load_lds(
      (const __attribute__((address_space(1))) unsigned int*)g,
      (__attribute__((address_space(3))) unsigned int*)l, 16, 0, 0);
}

// Bijective XCD-aware block swizzle (m204 form). Round-1 evidence:
// FETCH_SIZE 77 MB -> 31 MB on gemm_f16_uvb. Keep.
__device__ __forceinline__ void xcd_swizzle(int& bx, int& by) {
  int nx = gridDim.x;
  int nwg = nx * gridDim.y;
  int flat = by * nx + bx;
  int q = nwg >> 3, r = nwg & 7;
  int xcd = flat & 7, pos = flat >> 3;
  int lbid = (xcd < r) ? xcd * (q + 1) + pos
                       : r * (q + 1) + (xcd - r) * q + pos;
  bx = lbid % nx;
  by = lbid / nx;
}

// Round-5 GEMM structure: LDS-read-BW-bound diagnosis (rounds 1/2/4 all pin
// MfmaUtil ~20%; 8-wave/2x4 reads 48KB LDS per 128^2 K-iter vs ~77cyc MFMA).
// Fix: m97 shape — 4 waves (2x2) x 64x64/wave = 8 frag-reads for 16 MFMA
// (32KB/iter, 1.5x less LDS traffic). Schedule = round-2 proven counted-vmcnt
// 3-slot loop (stages are 4 loads now -> vmcnt(4)). launch_bounds(256,3)
// targets 3 blocks/CU (3 x 48KB = 144 <= 160 LDS).
// WAR audit (same as round-2, passing): prefetch at iter t writes slot
// (t+2)%3 which holds tile t-1, whose ds_reads were consumed by iter t-1's
// MFMAs (hw lgkm wait) before this wave passed the iter-t barrier.

#define STAGE4(slot) do {                                            \
    gll16(gAa, lAa + (slot) * BUF); gll16(gAb, lAb + (slot) * BUF);  \
    gll16(gBa, lBa + (slot) * BUF); gll16(gBb, lBb + (slot) * BUF);  \
    gAa += 32; gAb += 32; gBa += 32; gBb += 32; } while (0)

#define KLOOP4()                                                          \
  int ntile = K >> 5;                                                     \
  STAGE4(0);                                                              \
  if (ntile > 1) STAGE4(1);                                               \
  int cur = 0;                                                            \
  for (int t = 0; t < ntile; ++t) {                                       \
    if (t + 1 < ntile) asm volatile("s_waitcnt vmcnt(4)" ::: "memory");   \
    else               asm volatile("s_waitcnt vmcnt(0)" ::: "memory");   \
    __builtin_amdgcn_s_barrier();                                         \
    __builtin_amdgcn_sched_barrier(0);                                    \
    if (t + 2 < ntile) { int pf = cur + 2; if (pf >= 3) pf -= 3; STAGE4(pf); } \
    int fo = cur * (BUF / 8);                                             \
    f16x8 af[4], bfr[4];                                                  \
    _Pragma("unroll")                                                     \
    for (int tt = 0; tt < 4; ++tt) af[tt] = *(aptr[tt] + fo);             \
    _Pragma("unroll")                                                     \
    for (int tt = 0; tt < 4; ++tt) bfr[tt] = *(bptr[tt] + fo);            \
    _Pragma("unroll")                                                     \
    for (int mt = 0; mt < 4; ++mt)                                        \
      _Pragma("unroll")                                                   \
      for (int nt = 0; nt < 4; ++nt)                                      \
        acc[mt][nt] = __builtin_amdgcn_mfma_f32_16x16x32_f16(             \
            af[mt], bfr[nt], acc[mt][nt], 0, 0, 0);                       \
    cur = (cur == 2) ? 0 : cur + 1;                                       \
  }

// ============ f16 MFMA GEMM: C(MxN f32) = A(MxK f16,row) @ Bt(NxK f16,row)^T ======
__global__ __launch_bounds__(256, 3) void gemm_f16(
    const _Float16* __restrict__ A, int lda,
    const _Float16* __restrict__ Bt, int ldb,
    float* __restrict__ C, int ldc, int K,
    const float* __restrict__ bias, int mode,
    const int* __restrict__ ids)
{
  const int BUF = 128 * 32;
  __shared__ _Float16 As[3 * BUF];
  __shared__ _Float16 Bs[3 * BUF];
  int bx = blockIdx.x, by = blockIdx.y;
  xcd_swizzle(bx, by);
  int tid = threadIdx.x;
  int lane = tid & 63, w = tid >> 6;        // 4 waves
  int wm = w >> 1, wn = w & 1;              // 2x2 waves of 64x64
  int row0 = by * 128, col0 = bx * 128;

  // staging: call a covers rows 0-63, call b rows 64-127 (4 thr/row, 16B each)
  int m0 = tid >> 2;
  int k0e = (((tid & 3) - (m0 >> 1)) & 3) * 8;   // phys slot == tid
  const _Float16* gAa = A + (size_t)(row0 + m0) * lda + k0e;
  const _Float16* gAb = A + (size_t)(row0 + 64 + m0) * lda + k0e;
  const _Float16* gBa = Bt + (size_t)(col0 + m0) * ldb + k0e;
  const _Float16* gBb = Bt + (size_t)(col0 + 64 + m0) * ldb + k0e;
  const _Float16* lAa = As + (size_t)(w * 64) * 8;
  const _Float16* lAb = As + (size_t)(256 + w * 64) * 8;
  const _Float16* lBa = Bs + (size_t)(w * 64) * 8;
  const _Float16* lBb = Bs + (size_t)(256 + w * 64) * 8;

  int mrow = lane & 15, quad = lane >> 4;
  const f16x8* aptr[4];
  const f16x8* bptr[4];
#pragma unroll
  for (int t = 0; t < 4; ++t) {
    int ml = wm * 64 + t * 16 + mrow;
    aptr[t] = (const f16x8*)(As + (size_t)(ml * 4 + ((quad + (ml >> 1)) & 3)) * 8);
    int nl = wn * 64 + t * 16 + mrow;
    bptr[t] = (const f16x8*)(Bs + (size_t)(nl * 4 + ((quad + (nl >> 1)) & 3)) * 8);
  }

  f32x4 acc[4][4] = {};

  KLOOP4();

#pragma unroll
  for (int mt = 0; mt < 4; ++mt) {
#pragma unroll
    for (int nt = 0; nt < 4; ++nt) {
      int c = col0 + wn * 64 + nt * 16 + mrow;
      float bv = bias ? bias[c] : 0.0f;
#pragma unroll
      for (int reg = 0; reg < 4; ++reg) {
        int r = row0 + wm * 64 + mt * 16 + quad * 4 + reg;
        float val = acc[mt][nt][reg] + bv;
        if (mode == OP_STORE) {
          C[(size_t)r * ldc + c] = val;
        } else if (mode == OP_SILU) {
          C[(size_t)r * ldc + c] = silu_f(val);
        } else { // OP_RESID
          int hr = ids ? ids[r] : r;
          C[(size_t)hr * ldc + c] += val;
        }
      }
    }
  }
}

// ============ split-f16 GEMM for stage A: C = (Ah+Al)@(Bh+Bl)^T, 3-term ==========
// 2-buffer kept: 4 LDS arrays -> 3-buf would be 96 KB (1 block/CU). Swizzle only.
__global__ __launch_bounds__(512) void gemm_f16_split(
    const _Float16* __restrict__ Ah, const _Float16* __restrict__ Al, int lda,
    const _Float16* __restrict__ Bh, const _Float16* __restrict__ Bl, int ldb,
    float* __restrict__ C, int ldc, int K, const float* __restrict__ bias)
{
  const int BUF = 128 * 32;
  __shared__ _Float16 AsH[2 * BUF], AsL[2 * BUF];
  __shared__ _Float16 BsH[2 * BUF], BsL[2 * BUF];
  int bx = blockIdx.x, by = blockIdx.y;
  xcd_swizzle(bx, by);
  int tid = threadIdx.x;
  int lane = tid & 63, w = tid >> 6;
  int wm = w >> 1, wn = w & 1;
  int row0 = by * 128, col0 = bx * 128;

  int m0 = tid >> 2;
  int k0e = (((tid & 3) - (m0 >> 1)) & 3) * 8;
  size_t a0 = (size_t)(row0 + m0) * lda + k0e;
  size_t b0 = (size_t)(col0 + m0) * ldb + k0e;
  size_t l0 = (size_t)(w * 64) * 8;

  int mrow = lane & 15, quad = lane >> 4;
  size_t aoff[2], boff[4];
#pragma unroll
  for (int t = 0; t < 2; ++t) {
    int ml = wm * 32 + t * 16 + mrow;
    aoff[t] = (size_t)(ml * 4 + ((quad + (ml >> 1)) & 3)) * 8;
  }
#pragma unroll
  for (int nt = 0; nt < 4; ++nt) {
    int nl = wn * 64 + nt * 16 + mrow;
    boff[nt] = (size_t)(nl * 4 + ((quad + (nl >> 1)) & 3)) * 8;
  }

  f32x4 acc[2][4] = {};

  gll16(Ah + a0, AsH + l0); gll16(Al + a0, AsL + l0);
  gll16(Bh + b0, BsH + l0); gll16(Bl + b0, BsL + l0);
  a0 += 32; b0 += 32;

  for (int kt = 0; kt < K; kt += 32) {
    int cur = (kt >> 5) & 1;
    __syncthreads();
    if (kt + 32 < K) {
      size_t o = (size_t)(cur ^ 1) * BUF;
      gll16(Ah + a0, AsH + l0 + o); gll16(Al + a0, AsL + l0 + o);
      gll16(Bh + b0, BsH + l0 + o); gll16(Bl + b0, BsL + l0 + o);
      a0 += 32; b0 += 32;
    }
    size_t o = (size_t)cur * BUF;
    f16x8 ah[2], al_[2], bh[4], bl[4];
#pragma unroll
    for (int t = 0; t < 2; ++t) {
      ah[t]  = *(const f16x8*)(AsH + aoff[t] + o);
      al_[t] = *(const f16x8*)(AsL + aoff[t] + o);
    }
#pragma unroll
    for (int nt = 0; nt < 4; ++nt) {
      bh[nt] = *(const f16x8*)(BsH + boff[nt] + o);
      bl[nt] = *(const f16x8*)(BsL + boff[nt] + o);
    }
#pragma unroll
    for (int mt = 0; mt < 2; ++mt)
#pragma unroll
      for (int nt = 0; nt < 4; ++nt) {
        acc[mt][nt] = __builtin_amdgcn_mfma_f32_16x16x32_f16(
            ah[mt], bh[nt], acc[mt][nt], 0, 0, 0);
        acc[mt][nt] = __builtin_amdgcn_mfma_f32_16x16x32_f16(
            ah[mt], bl[nt], acc[mt][nt], 0, 0, 0);
        acc[mt][nt] = __builtin_amdgcn_mfma_f32_16x16x32_f16(
            al_[mt], bh[nt], acc[mt][nt], 0, 0, 0);
      }
  }

#pragma unroll
  for (int mt = 0; mt < 2; ++mt)
#pragma unroll
    for (int nt = 0; nt < 4; ++nt) {
      int c = col0 + wn * 64 + nt * 16 + mrow;
      float bv = bias ? bias[c] : 0.0f;
#pragma unroll
      for (int reg = 0; reg < 4; ++reg) {
        int r = row0 + wm * 32 + mt * 16 + quad * 4 + reg;
        C[(size_t)r * ldc + c] = acc[mt][nt][reg] + bv;
      }
    }
}

// ============ fused UVB GEMM: silu(n @ Wuv + buv) -> u/v (f16), base (f32) ==========
__global__ __launch_bounds__(256, 3) void gemm_f16_uvb(
    const _Float16* __restrict__ A, int lda,
    const _Float16* __restrict__ Bt,           // Wuv^T block (1792 x 512)
    int c0, int nu,
    _Float16* __restrict__ ub, _Float16* __restrict__ vb, float* __restrict__ baseb,
    int CH, int K, const float* __restrict__ buv)
{
  const int BUF = 128 * 32;
  __shared__ _Float16 As[3 * BUF];
  __shared__ _Float16 Bs[3 * BUF];
  int bx = blockIdx.x, by = blockIdx.y;
  xcd_swizzle(bx, by);
  int tid = threadIdx.x;
  int lane = tid & 63, w = tid >> 6;        // 4 waves
  int wm = w >> 1, wn = w & 1;              // 2x2 waves of 64x64
  int row0 = by * 128;

  int x = bx;
  int xl, regbase, ldc_, is_base = 0;
  _Float16* dst16 = nullptr;
  if (x < nu)            { xl = x;          regbase = c0;        dst16 = ub; ldc_ = CH; }
  else if (x < 2 * nu)   { xl = x - nu;     regbase = 768 + c0;  dst16 = vb; ldc_ = CH; }
  else                   { xl = x - 2 * nu; regbase = 1536;      is_base = 1; ldc_ = 256; }
  int brow0 = regbase + xl * 128;
  int dcol0 = xl * 128;

  int m0 = tid >> 2;
  int k0e = (((tid & 3) - (m0 >> 1)) & 3) * 8;
  const _Float16* gAa = A + (size_t)(row0 + m0) * lda + k0e;
  const _Float16* gAb = A + (size_t)(row0 + 64 + m0) * lda + k0e;
  const _Float16* gBa = Bt + (size_t)(brow0 + m0) * 512 + k0e;
  const _Float16* gBb = Bt + (size_t)(brow0 + 64 + m0) * 512 + k0e;
  const _Float16* lAa = As + (size_t)(w * 64) * 8;
  const _Float16* lAb = As + (size_t)(256 + w * 64) * 8;
  const _Float16* lBa = Bs + (size_t)(w * 64) * 8;
  const _Float16* lBb = Bs + (size_t)(256 + w * 64) * 8;

  int mrow = lane & 15, quad = lane >> 4;
  const f16x8* aptr[4];
  const f16x8* bptr[4];
#pragma unroll
  for (int t = 0; t < 4; ++t) {
    int ml = wm * 64 + t * 16 + mrow;
    aptr[t] = (const f16x8*)(As + (size_t)(ml * 4 + ((quad + (ml >> 1)) & 3)) * 8);
    int nl = wn * 64 + t * 16 + mrow;
    bptr[t] = (const f16x8*)(Bs + (size_t)(nl * 4 + ((quad + (nl >> 1)) & 3)) * 8);
  }

  f32x4 acc[4][4] = {};

  KLOOP4();

#pragma unroll
  for (int mt = 0; mt < 4; ++mt) {
#pragma unroll
    for (int nt = 0; nt < 4; ++nt) {
      int lc = wn * 64 + nt * 16 + mrow;
      float bv = buv[brow0 + lc];
#pragma unroll
      for (int reg = 0; reg < 4; ++reg) {
        int r = row0 + wm * 64 + mt * 16 + quad * 4 + reg;
        float val = silu_f(acc[mt][nt][reg] + bv);
        if (is_base) baseb[(size_t)r * 256 + dcol0 + lc] = val;
        else         dst16[(size_t)r * ldc_ + dcol0 + lc] = (_Float16)val;
      }
    }
  }
}

// ============ fused attention: a = relu(qk^T/64)^2 in LDS, then t = (a@v)*u =========
// grid (nch, n_buckets): each wg recomputes scores (cheap) and does ech cols of PV.
__global__ __launch_bounds__(256) void attnapply_fused(
    const float* __restrict__ base, const float* __restrict__ gb,
    const float* __restrict__ bb, const _Float16* __restrict__ v,
    const _Float16* __restrict__ u, _Float16* __restrict__ t, int CH, int ech)
{
  __shared__ _Float16 smem[3 * 64 * 72];
  _Float16* qs = smem;
  _Float16* ks = smem + 64 * 72;
  _Float16* al = smem + 2 * 64 * 72;
  _Float16* vT = smem;               // phase B aliases qs (dead)

  int bx = blockIdx.x, by = blockIdx.y;
  xcd_swizzle(bx, by);
  int g = by, tid = threadIdx.x;
  int e_lo = bx * ech, e_hi = e_lo + ech;
  int lane = tid & 63, w = tid >> 6;
  int mrow = lane & 15, quad = lane >> 4;
  int srow = tid >> 2, scol = (tid & 3) * 16;

  // ---- phase A: scores ----
  f32x4 acc[4] = {};
  for (int s0 = 0; s0 < 256; s0 += 64) {
    const float* bp = base + ((size_t)g * 64 + srow) * 256 + s0 + scol;
#pragma unroll
    for (int j4 = 0; j4 < 4; ++j4) {
      float4 xv = *(const float4*)(bp + j4 * 4);
      float xx[4] = {xv.x, xv.y, xv.z, xv.w};
#pragma unroll
      for (int j = 0; j < 4; ++j) {
        int s = s0 + scol + j4 * 4 + j;
        qs[srow * 72 + scol + j4 * 4 + j] = (_Float16)(xx[j] * gb[s] + bb[s]);
        ks[srow * 72 + scol + j4 * 4 + j] = (_Float16)(xx[j] * gb[256 + s] + bb[256 + s]);
      }
    }
    __syncthreads();
#pragma unroll
    for (int ks2 = 0; ks2 < 2; ++ks2) {
      f16x8 aq = *(const f16x8*)(qs + (w * 16 + mrow) * 72 + ks2 * 32 + quad * 8);
#pragma unroll
      for (int nt = 0; nt < 4; ++nt) {
        f16x8 bk = *(const f16x8*)(ks + (nt * 16 + mrow) * 72 + ks2 * 32 + quad * 8);
        acc[nt] = __builtin_amdgcn_mfma_f32_16x16x32_f16(aq, bk, acc[nt], 0, 0, 0);
      }
    }
    __syncthreads();
  }
#pragma unroll
  for (int nt = 0; nt < 4; ++nt)
#pragma unroll
    for (int reg = 0; reg < 4; ++reg) {
      float val = acc[nt][reg] * (1.0f / 64.0f);
      val = val > 0.0f ? val : 0.0f;
      val = val * val;
      al[(w * 16 + quad * 4 + reg) * 72 + nt * 16 + mrow] = (_Float16)val;
    }
  __syncthreads();

  // ---- phase B: t = (a @ v) * u on [e_lo, e_hi) ----
  for (int e0 = e_lo; e0 < e_hi; e0 += 64) {
    const _Float16* vp = v + ((size_t)g * 64 + srow) * CH + e0 + scol;
    f16x8 x0 = *(const f16x8*)vp;
    f16x8 x1 = *(const f16x8*)(vp + 8);
#pragma unroll
    for (int j = 0; j < 8; ++j) {
      vT[(scol + j) * 72 + srow] = x0[j];
      vT[(scol + 8 + j) * 72 + srow] = x1[j];
    }
    __syncthreads();
    f32x4 acc2[4] = {};
#pragma unroll
    for (int ks2 = 0; ks2 < 2; ++ks2) {
      f16x8 af = *(const f16x8*)(al + (w * 16 + mrow) * 72 + ks2 * 32 + quad * 8);
#pragma unroll
      for (int nt = 0; nt < 4; ++nt) {
        f16x8 bf = *(const f16x8*)(vT + (nt * 16 + mrow) * 72 + ks2 * 32 + quad * 8);
        acc2[nt] = __builtin_amdgcn_mfma_f32_16x16x32_f16(af, bf, acc2[nt], 0, 0, 0);
      }
    }
#pragma unroll
    for (int nt = 0; nt < 4; ++nt)
#pragma unroll
      for (int reg = 0; reg < 4; ++reg) {
        int row = w * 16 + quad * 4 + reg;
        int col = e0 + nt * 16 + mrow;
        size_t idx = ((size_t)g * 64 + row) * CH + col;
        t[idx] = (_Float16)(acc2[nt][reg] * (float)u[idx]);
      }
    __syncthreads();
  }
}

// ---------------- generic fp32 GEMM (fallback stage A + small tails) ----------------
__global__ __launch_bounds__(256) void gemm_f32(
    const float* __restrict__ A, int lda,
    const float* __restrict__ B, int ldb,
    float* __restrict__ C, int ldc,
    int M, int N, int K,
    const float* __restrict__ bias, int mode,
    const int* __restrict__ ids,
    const float* __restrict__ X,
    const float* __restrict__ alpha)
{
  __shared__ float As[16][68];
  __shared__ float Bs[16][68];
  int tid = threadIdx.x;
  int tx = tid & 15, ty = tid >> 4;
  int col0 = blockIdx.x * 64, row0 = blockIdx.y * 64;
  float acc[4][4] = {};
  int arow = tid >> 2;
  int ak   = (tid & 3) * 4;
  int bk   = tid >> 4;
  int bn   = (tid & 15) * 4;

  for (int kt = 0; kt < K; kt += 16) {
    float4 av = make_float4(0.f, 0.f, 0.f, 0.f);
    if (row0 + arow < M)
      av = *(const float4*)&A[(size_t)(row0 + arow) * lda + kt + ak];
    As[ak + 0][arow] = av.x; As[ak + 1][arow] = av.y;
    As[ak + 2][arow] = av.z; As[ak + 3][arow] = av.w;
    float4 bv = *(const float4*)&B[(size_t)(kt + bk) * ldb + col0 + bn];
    *(float4*)&Bs[bk][bn] = bv;
    __syncthreads();
#pragma unroll
    for (int k = 0; k < 16; ++k) {
      const float4 a4 = *(const float4*)&As[k][ty * 4];
      const float4 b4 = *(const float4*)&Bs[k][tx * 4];
      float a_[4] = {a4.x, a4.y, a4.z, a4.w};
      float b_[4] = {b4.x, b4.y, b4.z, b4.w};
#pragma unroll
      for (int i = 0; i < 4; ++i)
#pragma unroll
        for (int j = 0; j < 4; ++j)
          acc[i][j] = fmaf(a_[i], b_[j], acc[i][j]);
    }
    __syncthreads();
  }

#pragma unroll
  for (int i = 0; i < 4; ++i) {
    int r = row0 + ty * 4 + i;
    if (r >= M) continue;
#pragma unroll
    for (int j = 0; j < 4; ++j) {
      int c = col0 + tx * 4 + j;
      float val = acc[i][j] + (bias ? bias[c] : 0.0f);
      if (mode == OP_STORE) {
        C[(size_t)r * ldc + c] = val;
      } else if (mode == OP_SILU) {
        C[(size_t)r * ldc + c] = silu_f(val);
      } else if (mode == OP_RESID) {
        int hr = ids ? ids[r] : r;
        C[(size_t)hr * ldc + c] += val;
      } else { // OP_TR
        C[(size_t)r * ldc + c] = X[(size_t)r * ldc + c] + gelu_f(val) * alpha[0];
      }
    }
  }
}

// ---------------- weight transpose + cast ----------------
__global__ __launch_bounds__(256) void transpose_cast(
    const float* __restrict__ in, _Float16* __restrict__ out, int K, int N)
{
  in  += (size_t)blockIdx.z * K * N;
  out += (size_t)blockIdx.z * K * N;
  __shared__ float t[32][33];
  int k0 = blockIdx.y * 32, n0 = blockIdx.x * 32;
  int tx = threadIdx.x & 31, ty = threadIdx.x >> 5;
  for (int i = ty; i < 32; i += 8) {
    int k = k0 + i, n = n0 + tx;
    t[i][tx] = (k < K && n < N) ? in[(size_t)k * N + n] : 0.0f;
  }
  __syncthreads();
  for (int i = ty; i < 32; i += 8) {
    int n = n0 + i, k = k0 + tx;
    if (n < N && k < K) out[(size_t)n * K + k] = (_Float16)t[tx][i];
  }
}

__global__ __launch_bounds__(256) void transpose_split(
    const float* __restrict__ in, _Float16* __restrict__ hi,
    _Float16* __restrict__ lo, int K, int N)
{
  __shared__ float t[32][33];
  int k0 = blockIdx.y * 32, n0 = blockIdx.x * 32;
  int tx = threadIdx.x & 31, ty = threadIdx.x >> 5;
  for (int i = ty; i < 32; i += 8) {
    int k = k0 + i, n = n0 + tx;
    t[i][tx] = (k < K && n < N) ? in[(size_t)k * N + n] : 0.0f;
  }
  __syncthreads();
  for (int i = ty; i < 32; i += 8) {
    int n = n0 + i, k = k0 + tx;
    if (n < N && k < K) {
      float x = t[tx][i];
      _Float16 h = (_Float16)x;
      hi[(size_t)n * K + k] = h;
      lo[(size_t)n * K + k] = (_Float16)(x - (float)h);
    }
  }
}

__global__ __launch_bounds__(256) void split_f16_kernel(
    const float* __restrict__ in, _Float16* __restrict__ hi,
    _Float16* __restrict__ lo, int n)
{
  int i = blockIdx.x * 256 + threadIdx.x;
  if (i < n) {
    float x = in[i];
    _Float16 h = (_Float16)x;
    hi[i] = h;
    lo[i] = (_Float16)(x - (float)h);
  }
}

// ---------------- layernorm over 512 + optional gather/leaky/norm2-out ----------
template <typename OUT>
__global__ __launch_bounds__(256) void ln_kernel(
    const float* __restrict__ src, const int* __restrict__ ids,
    OUT* __restrict__ dst, const float* __restrict__ g,
    const float* __restrict__ b, float eps, int leaky,
    float* __restrict__ nrm2)
{
  int r = blockIdx.x;
  int sr = ids ? ids[r] : r;
  int tid = threadIdx.x;
  float v0 = src[(size_t)sr * 512 + tid];
  float v1 = src[(size_t)sr * 512 + tid + 256];
  __shared__ float red[256], red2[256];
  red[tid] = v0 + v1;
  red2[tid] = v0 * v0 + v1 * v1;
  __syncthreads();
  for (int s = 128; s > 0; s >>= 1) {
    if (tid < s) { red[tid] += red[tid + s]; red2[tid] += red2[tid + s]; }
    __syncthreads();
  }
  float mean = red[0] * (1.0f / 512.0f);
  float var  = red2[0] * (1.0f / 512.0f) - mean * mean;
  float rs = rsqrtf(var + eps);
  float o0 = (v0 - mean) * rs * g[tid] + b[tid];
  float o1 = (v1 - mean) * rs * g[tid + 256] + b[tid + 256];
  if (leaky) {
    o0 = o0 > 0.0f ? o0 : 0.1f * o0;
    o1 = o1 > 0.0f ? o1 : 0.1f * o1;
  }
  dst[(size_t)r * 512 + tid] = (OUT)o0;
  dst[(size_t)r * 512 + tid + 256] = (OUT)o1;
  if (nrm2) {
    __syncthreads();
    red[tid] = o0 * o0 + o1 * o1;
    __syncthreads();
    for (int s = 128; s > 0; s >>= 1) {
      if (tid < s) red[tid] += red[tid + s];
      __syncthreads();
    }
    if (tid == 0) nrm2[r] = red[0];
  }
}

// ---------------- row gather: dst[r] = src[ids[r]] ----------------
__global__ __launch_bounds__(128) void permute_rows(
    const float* __restrict__ src, const int* __restrict__ ids,
    float* __restrict__ dst)
{
  int r = blockIdx.x, sr = ids[r];
  const float4* s = (const float4*)(src + (size_t)sr * 512);
  float4* d = (float4*)(dst + (size_t)r * 512);
  d[threadIdx.x] = s[threadIdx.x];
}

// ---------------- bitonic argsort of 4096 keys per sample ----------------
__global__ __launch_bounds__(1024) void sort_kernel(const float* __restrict__ norm2,
                                                    int* __restrict__ ids)
{
  __shared__ float key[4096];
  __shared__ int   val[4096];
  int s = blockIdx.x, tid = threadIdx.x;
  for (int i = tid; i < 4096; i += 1024) { key[i] = norm2[s * 4096 + i]; val[i] = i; }
  __syncthreads();
  for (int len = 2; len <= 4096; len <<= 1) {
    for (int j = len >> 1; j > 0; j >>= 1) {
      for (int t = tid; t < 2048; t += 1024) {
        int i1 = (t << 1) - (t & (j - 1));
        int i2 = i1 + j;
        bool up = ((i1 & len) == 0);
        float ka = key[i1], kb = key[i2];
        int va = val[i1], vb = val[i2];
        bool gt = (ka > kb) || (ka == kb && va > vb);
        if (gt == up) {
          key[i1] = kb; key[i2] = ka;
          val[i1] = vb; val[i2] = va;
        }
      }
      __syncthreads();
    }
  }
  for (int i = tid; i < 4096; i += 1024) ids[s * 4096 + i] = s * 4096 + val[i];
}

// ---------------- mean over groups of 64 rows (optional gather) ----------------
__global__ __launch_bounds__(256) void bucketmean_kernel(
    const float* __restrict__ src, const int* __restrict__ ids,
    float* __restrict__ dst)
{
  int g = blockIdx.x, tid = threadIdx.x;
  float s0 = 0.0f, s1 = 0.0f;
  for (int i = 0; i < 64; ++i) {
    int r = g * 64 + i;
    if (ids) r = ids[r];
    s0 += src[(size_t)r * 512 + tid];
    s1 += src[(size_t)r * 512 + tid + 256];
  }
  dst[(size_t)g * 512 + tid] = s0 * (1.0f / 64.0f);
  dst[(size_t)g * 512 + tid + 256] = s1 * (1.0f / 64.0f);
}

__global__ void avg_kernel(const float* __restrict__ a, const float* __restrict__ b,
                           float* __restrict__ o, int n)
{
  int i = blockIdx.x * 256 + threadIdx.x;
  if (i < n) o[i] = 0.5f * (a[i] + b[i]);
}

__global__ void out_kernel(const float* __restrict__ y, const float* __restrict__ W,
                           const float* __restrict__ b, float* __restrict__ out)
{
  int tid = threadIdx.x;
  if (tid < 8) {
    int s = tid >> 1, j = tid & 1;
    float acc = b[j];
    for (int d = 0; d < 512; ++d) acc += y[s * 512 + d] * W[d * 2 + j];
    out[s * 2 + j] = acc;
  }
}

extern "C" void kernel_launch(void* const* d_in, const int* in_sizes, int n_in,
                              void* d_out, int out_size, void* d_ws, size_t ws_size,
                              hipStream_t stream)
{
  const float* xs       = (const float*)d_in[0];
  const float* W_in     = (const float*)d_in[1];
  const float* b_in     = (const float*)d_in[2];
  const float* ln_in_g  = (const float*)d_in[3];
  const float* ln_in_b  = (const float*)d_in[4];
  const float* blk_ln_g = (const float*)d_in[5];
  const float* blk_ln_b = (const float*)d_in[6];
  const float* blk_Wuv  = (const float*)d_in[7];
  const float* blk_buv  = (const float*)d_in[8];
  const float* blk_gam  = (const float*)d_in[9];
  const float* blk_bet  = (const float*)d_in[10];
  const float* blk_Wo   = (const float*)d_in[11];
  const float* blk_bo   = (const float*)d_in[12];
  const float* tr_W     = (const float*)d_in[13];
  const float* tr_b     = (const float*)d_in[14];
  const float* tr_a     = (const float*)d_in[15];
  const float* tr2_W    = (const float*)d_in[16];
  const float* tr2_b    = (const float*)d_in[17];
  const float* tr2_a    = (const float*)d_in[18];
  const float* out_W    = (const float*)d_in[19];
  const float* out_b    = (const float*)d_in[20];
  float* outp = (float*)d_out;

  const size_t R1 = R1C;

  // ---- persistent carve ----
  char* wsb = (char*)d_ws;
  size_t off = 0;
  auto carve = [&](size_t bytes) {
    char* r = wsb + off;
    off = (off + bytes + 255) & ~(size_t)255;
    return (void*)r;
  };
  float* h      = (float*)carve(R1 * 512 * 4);   // unsorted residual (pre-permute)
  float* hslot  = (float*)carve(R1 * 512 * 4);   // sorted mode: hs; fallback: nb
  float* norm2b = (float*)carve(R1 * 4);
  int*   idsb   = (int*)carve(R1 * 4);
  float* gy     = (float*)carve((size_t)256 * 512 * 4);
  float* tl     = (float*)carve((size_t)256 * 512 * 4);
  float* gy2    = (float*)carve(4 * 512 * 4);
  float* ys0    = (float*)carve(4 * 512 * 4);
  float* ys1    = (float*)carve(4 * 512 * 4);
  float* yv     = (float*)carve(4 * 512 * 4);
  float* y2     = (float*)carve(4 * 512 * 4);
  _Float16* Wuvt = (_Float16*)carve((size_t)6 * 1792 * 512 * 2);
  _Float16* Wot  = (_Float16*)carve((size_t)6 * 512 * 768 * 2);
  size_t persistent = off;

  // ---- union sizing ----
  size_t stageA_sorted = 2 * R1 * 768 * 2 + 2 * (size_t)512 * 768 * 2 + R1 * 512 * 4 + 2048;
  size_t block768 = R1 * 256 * 4 + 3 * R1 * (size_t)768 * 2 + 2048;
  size_t un_sorted = stageA_sorted > block768 ? stageA_sorted : block768;
  bool sorted_mode = (persistent + un_sorted + 4096 <= ws_size);

  int CH = 768;
  bool splitA = true;
  if (!sorted_mode) {
    size_t stageA_fb = 2 * R1 * 768 * 2 + 2 * (size_t)512 * 768 * 2 + 1024;
    auto block_bytes = [&](size_t ch) {
      return R1 * 256 * 4 + 3 * R1 * ch * 2 + 2048;
    };
    CH = 0; splitA = false;
    const int cand[4] = {768, 384, 256, 128};
    for (int ci = 0; ci < 4; ++ci) {
      size_t bb2 = block_bytes(cand[ci]);
      size_t un2 = bb2 > stageA_fb ? bb2 : stageA_fb;
      if (persistent + un2 + 4096 <= ws_size) { CH = cand[ci]; splitA = true; break; }
    }
    if (!CH) {
      for (int ci = 0; ci < 4; ++ci)
        if (persistent + block_bytes(cand[ci]) + 4096 <= ws_size) { CH = cand[ci]; break; }
      if (!CH) CH = 128;
    }
  }
  int nu = CH / 128;
  int ech = CH >= 256 ? 256 : CH;     // attnapply chunk width
  int nch = CH / ech;

  char* un = wsb + ((persistent + 255) & ~(size_t)255);
  // stage-A overlay
  _Float16* xs_hi = (_Float16*)un;
  _Float16* xs_lo = xs_hi + R1 * 768;
  _Float16* Wt_hi = xs_lo + R1 * 768;
  _Float16* Wt_lo = Wt_hi + (size_t)512 * 768;
  float*    nbA   = sorted_mode ? (float*)(Wt_lo + (size_t)512 * 768) : hslot;
  // block overlay
  float*    baseb = (float*)un;
  _Float16* ub    = (_Float16*)(un + R1 * 256 * 4);
  _Float16* vb    = ub + R1 * (size_t)CH;
  _Float16* tb    = vb + R1 * (size_t)CH;
  _Float16* nbuf  = sorted_mode ? tb : (_Float16*)hslot;
  float* hres = sorted_mode ? hslot : h;
  const int* blkids = sorted_mode ? nullptr : idsb;

  dim3 blk(256);
  dim3 blk5(512);

  // ---- weight prep ----
  transpose_cast<<<dim3(56, 16, 6), blk, 0, stream>>>(blk_Wuv, Wuvt, 512, 1792);
  transpose_cast<<<dim3(16, 24, 6), blk, 0, stream>>>(blk_Wo, Wot, 768, 512);

  // ---- Stage A ----
  if (splitA) {
    split_f16_kernel<<<(int)(R1 * 768 / 256), blk, 0, stream>>>(xs, xs_hi, xs_lo,
                                                                (int)(R1 * 768));
    transpose_split<<<dim3(16, 24, 1), blk, 0, stream>>>(W_in, Wt_hi, Wt_lo, 768, 512);
    gemm_f16_split<<<dim3(4, 128), blk5, 0, stream>>>(xs_hi, xs_lo, 768,
        Wt_hi, Wt_lo, 768, nbA, 512, 768, b_in);
  } else {
    gemm_f32<<<dim3(8, 256), blk, 0, stream>>>(xs, 768, W_in, 512, nbA, 512,
        16384, 512, 768, b_in, OP_STORE, nullptr, nullptr, nullptr);
  }
  ln_kernel<float><<<16384, 256, 0, stream>>>(nbA, nullptr, h, ln_in_g, ln_in_b,
                                              1e-8f, 1, norm2b);
  sort_kernel<<<4, 1024, 0, stream>>>(norm2b, idsb);
  if (sorted_mode)
    permute_rows<<<16384, 128, 0, stream>>>(h, idsb, hres);

  // ---- Iteration 1: 6 subnet blocks over 256 buckets ----
  for (int b = 0; b < 6; ++b) {
    const _Float16* Wuv_t = Wuvt + (size_t)b * 1792 * 512;
    const float*    buv   = blk_buv + b * 1792;
    const _Float16* Wo_t  = Wot + (size_t)b * 512 * 768;
    ln_kernel<_Float16><<<16384, 256, 0, stream>>>(hres, blkids, nbuf,
        blk_ln_g + b * 512, blk_ln_b + b * 512, 1e-5f, 0, nullptr);
    for (int c0 = 0; c0 < 768; c0 += CH) {
      int incl = (c0 == 0) ? 2 : 0;
      gemm_f16_uvb<<<dim3(2 * nu + incl, 128), blk, 0, stream>>>(nbuf, 512, Wuv_t,
          c0, nu, ub, vb, baseb, CH, 512, buv);
      attnapply_fused<<<dim3(nch, 256), blk, 0, stream>>>(baseb, blk_gam + b * 512,
          blk_bet + b * 512, vb, ub, tb, CH, ech);
      const float* bo = (c0 + CH == 768) ? (blk_bo + b * 512) : nullptr;
      gemm_f16<<<dim3(4, 128), blk, 0, stream>>>(tb, CH, Wo_t + c0, 768,
          hres, 512, CH, bo, OP_RESID, blkids);
    }
  }
  bucketmean_kernel<<<256, 256, 0, stream>>>(hres, blkids, gy);

  // ---- ys0 = mean_buckets(tr_layer(gy)) ----
  gemm_f32<<<dim3(8, 4), blk, 0, stream>>>(gy, 512, tr_W, 512, tl, 512,
      256, 512, 512, tr_b, OP_TR, nullptr, gy, tr_a);
  bucketmean_kernel<<<4, 256, 0, stream>>>(tl, nullptr, ys0);

  // ---- Iteration 2: 64 rows/sample == 1 bucket; sort permutation cancels ----
  for (int b = 0; b < 6; ++b) {
    const _Float16* Wuv_t = Wuvt + (size_t)b * 1792 * 512;
    const float*    buv   = blk_buv + b * 1792;
    const _Float16* Wo_t  = Wot + (size_t)b * 512 * 768;
    ln_kernel<_Float16><<<256, 256, 0, stream>>>(gy, nullptr, nbuf, blk_ln_g + b * 512,
                                                 blk_ln_b + b * 512, 1e-5f, 0, nullptr);
    for (int c0 = 0; c0 < 768; c0 += CH) {
      int incl = (c0 == 0) ? 2 : 0;
      gemm_f16_uvb<<<dim3(2 * nu + incl, 2), blk, 0, stream>>>(nbuf, 512, Wuv_t,
          c0, nu, ub, vb, baseb, CH, 512, buv);
      attnapply_fused<<<dim3(nch, 4), blk, 0, stream>>>(baseb, blk_gam + b * 512,
          blk_bet + b * 512, vb, ub, tb, CH, ech);
      const float* bo = (c0 + CH == 768) ? (blk_bo + b * 512) : nullptr;
      gemm_f16<<<dim3(4, 2), blk, 0, stream>>>(tb, CH, Wo_t + c0, 768,
          gy, 512, CH, bo, OP_RESID, nullptr);
    }
  }
  bucketmean_kernel<<<4, 256, 0, stream>>>(gy, nullptr, gy2);

  // ---- tails ----
  gemm_f32<<<dim3(8, 1), blk, 0, stream>>>(gy2, 512, tr_W, 512, ys1, 512,
      4, 512, 512, tr_b, OP_TR, nullptr, gy2, tr_a);
  avg_kernel<<<8, 256, 0, stream>>>(ys0, ys1, yv, 2048);
  gemm_f32<<<dim3(8, 1), blk, 0, stream>>>(yv, 512, tr2_W, 512, y2, 512,
      4, 512, 512, tr2_b, OP_TR, nullptr, yv, tr2_a);
  out_kernel<<<1, 64, 0, stream>>>(y2, out_W, out_b, outp);
}

// Round 6
// 1589.418 us; speedup vs baseline: 1.1052x; 1.1052x over previous
//
#include <hip/hip_runtime.h>
#include <math.h>

#define R1C 16384

enum { OP_STORE = 0, OP_SILU = 1, OP_RESID = 2, OP_TR = 3 };

typedef _Float16 f16x8 __attribute__((ext_vector_type(8)));
typedef float f32x4 __attribute__((ext_vector_type(4)));

__device__ __forceinline__ float silu_f(float x) { return x / (1.0f + __expf(-x)); }
__device__ __forceinline__ float gelu_f(float x) {
  return 0.5f * x * (1.0f + erff(x * 0.70710678118654752f));
}

__device__ __forceinline__ void gll16(const void* g, const void* l) {
  __builtin_amdgcn_global_load_lds(
      (const __attribute__((address_space(1))) unsigned int*)g,
      (__attribute__((address_space(3))) unsigned int*)l, 16, 0, 0);
}

// Bijective XCD-aware block swizzle (m204 form). Round-1 evidence:
// FETCH_SIZE 77 MB -> 31 MB on gemm_f16_uvb. Keep.
__device__ __forceinline__ void xcd_swizzle(int& bx, int& by) {
  int nx = gridDim.x;
  int nwg = nx * gridDim.y;
  int flat = by * nx + bx;
  int q = nwg >> 3, r = nwg & 7;
  int xcd = flat & 7, pos = flat >> 3;
  int lbid = (xcd < r) ? xcd * (q + 1) + pos
                       : r * (q + 1) + (xcd - r) * q + pos;
  bx = lbid % nx;
  by = lbid / nx;
}

// GEMM structure: ROUND-2 state (best measured: uvb 58us, total 1595us).
// 8 waves x (2x4) 16x16 tiles; 3-deep LDS rotation, 2-ahead prefetch with
// counted vmcnt(2); one barrier per K-iter. Rounds 3/4/5 (reg-pipeline,
// 4-wave 64x64 shapes) all regressed -> structure banked, do not re-roll.

// ============ f16 MFMA GEMM: C(MxN f32) = A(MxK f16,row) @ Bt(NxK f16,row)^T ======
__global__ __launch_bounds__(512) void gemm_f16(
    const _Float16* __restrict__ A, int lda,
    const _Float16* __restrict__ Bt, int ldb,
    float* __restrict__ C, int ldc, int K,
    const float* __restrict__ bias, int mode,
    const int* __restrict__ ids)
{
  const int BUF = 128 * 32;
  __shared__ _Float16 As[3 * BUF];
  __shared__ _Float16 Bs[3 * BUF];
  int bx = blockIdx.x, by = blockIdx.y;
  xcd_swizzle(bx, by);
  int tid = threadIdx.x;
  int lane = tid & 63, w = tid >> 6;        // 8 waves
  int wm = w >> 1, wn = w & 1;              // wm 0..3 (32-row strip), wn 0..1
  int row0 = by * 128, col0 = bx * 128;

  int m0 = tid >> 2;
  int k0e = (((tid & 3) - (m0 >> 1)) & 3) * 8;
  const _Float16* gA0 = A + (size_t)(row0 + m0) * lda + k0e;
  const _Float16* gB0 = Bt + (size_t)(col0 + m0) * ldb + k0e;
  const _Float16* lA0 = As + (size_t)(w * 64) * 8;   // wave-uniform base; slot = tid
  const _Float16* lB0 = Bs + (size_t)(w * 64) * 8;

  int mrow = lane & 15, quad = lane >> 4;
  const f16x8* aptr[2];
  const f16x8* bptr[4];
#pragma unroll
  for (int t = 0; t < 2; ++t) {
    int ml = wm * 32 + t * 16 + mrow;
    aptr[t] = (const f16x8*)(As + (size_t)(ml * 4 + ((quad + (ml >> 1)) & 3)) * 8);
  }
#pragma unroll
  for (int nt = 0; nt < 4; ++nt) {
    int nl = wn * 64 + nt * 16 + mrow;
    bptr[nt] = (const f16x8*)(Bs + (size_t)(nl * 4 + ((quad + (nl >> 1)) & 3)) * 8);
  }

  f32x4 acc[2][4] = {};

  int ntile = K >> 5;
  // prologue: stage tiles 0 and 1 (2 vmcnt events per stage per wave)
  gll16(gA0, lA0); gll16(gB0, lB0);
  gA0 += 32; gB0 += 32;
  if (ntile > 1) {
    gll16(gA0, lA0 + BUF); gll16(gB0, lB0 + BUF);
    gA0 += 32; gB0 += 32;
  }

  int cur = 0;
  for (int t = 0; t < ntile; ++t) {
    // wait for stage(t) to land; leave stage(t+1)'s 2 loads in flight.
    if (t + 1 < ntile) asm volatile("s_waitcnt vmcnt(2)" ::: "memory");
    else               asm volatile("s_waitcnt vmcnt(0)" ::: "memory");
    __builtin_amdgcn_s_barrier();
    __builtin_amdgcn_sched_barrier(0);
    if (t + 2 < ntile) {
      int pf = cur + 2; if (pf >= 3) pf -= 3;
      gll16(gA0, lA0 + pf * BUF); gll16(gB0, lB0 + pf * BUF);
      gA0 += 32; gB0 += 32;
    }
    int fo = cur * (BUF / 8);
    f16x8 af[2], bfr[4];
#pragma unroll
    for (int tt = 0; tt < 2; ++tt) af[tt] = *(aptr[tt] + fo);
#pragma unroll
    for (int nt = 0; nt < 4; ++nt) bfr[nt] = *(bptr[nt] + fo);
#pragma unroll
    for (int mt = 0; mt < 2; ++mt)
#pragma unroll
      for (int nt = 0; nt < 4; ++nt)
        acc[mt][nt] = __builtin_amdgcn_mfma_f32_16x16x32_f16(
            af[mt], bfr[nt], acc[mt][nt], 0, 0, 0);
    cur = (cur == 2) ? 0 : cur + 1;
  }

#pragma unroll
  for (int mt = 0; mt < 2; ++mt) {
#pragma unroll
    for (int nt = 0; nt < 4; ++nt) {
      int c = col0 + wn * 64 + nt * 16 + mrow;
      float bv = bias ? bias[c] : 0.0f;
#pragma unroll
      for (int reg = 0; reg < 4; ++reg) {
        int r = row0 + wm * 32 + mt * 16 + quad * 4 + reg;
        float val = acc[mt][nt][reg] + bv;
        if (mode == OP_STORE) {
          C[(size_t)r * ldc + c] = val;
        } else if (mode == OP_SILU) {
          C[(size_t)r * ldc + c] = silu_f(val);
        } else { // OP_RESID
          int hr = ids ? ids[r] : r;
          C[(size_t)hr * ldc + c] += val;
        }
      }
    }
  }
}

// ============ split-f16 GEMM for stage A: C = (Ah+Al)@(Bh+Bl)^T, 3-term ==========
// 2-buffer kept: 4 LDS arrays -> 3-buf would be 96 KB (1 block/CU). Swizzle only.
__global__ __launch_bounds__(512) void gemm_f16_split(
    const _Float16* __restrict__ Ah, const _Float16* __restrict__ Al, int lda,
    const _Float16* __restrict__ Bh, const _Float16* __restrict__ Bl, int ldb,
    float* __restrict__ C, int ldc, int K, const float* __restrict__ bias)
{
  const int BUF = 128 * 32;
  __shared__ _Float16 AsH[2 * BUF], AsL[2 * BUF];
  __shared__ _Float16 BsH[2 * BUF], BsL[2 * BUF];
  int bx = blockIdx.x, by = blockIdx.y;
  xcd_swizzle(bx, by);
  int tid = threadIdx.x;
  int lane = tid & 63, w = tid >> 6;
  int wm = w >> 1, wn = w & 1;
  int row0 = by * 128, col0 = bx * 128;

  int m0 = tid >> 2;
  int k0e = (((tid & 3) - (m0 >> 1)) & 3) * 8;
  size_t a0 = (size_t)(row0 + m0) * lda + k0e;
  size_t b0 = (size_t)(col0 + m0) * ldb + k0e;
  size_t l0 = (size_t)(w * 64) * 8;

  int mrow = lane & 15, quad = lane >> 4;
  size_t aoff[2], boff[4];
#pragma unroll
  for (int t = 0; t < 2; ++t) {
    int ml = wm * 32 + t * 16 + mrow;
    aoff[t] = (size_t)(ml * 4 + ((quad + (ml >> 1)) & 3)) * 8;
  }
#pragma unroll
  for (int nt = 0; nt < 4; ++nt) {
    int nl = wn * 64 + nt * 16 + mrow;
    boff[nt] = (size_t)(nl * 4 + ((quad + (nl >> 1)) & 3)) * 8;
  }

  f32x4 acc[2][4] = {};

  gll16(Ah + a0, AsH + l0); gll16(Al + a0, AsL + l0);
  gll16(Bh + b0, BsH + l0); gll16(Bl + b0, BsL + l0);
  a0 += 32; b0 += 32;

  for (int kt = 0; kt < K; kt += 32) {
    int cur = (kt >> 5) & 1;
    __syncthreads();
    if (kt + 32 < K) {
      size_t o = (size_t)(cur ^ 1) * BUF;
      gll16(Ah + a0, AsH + l0 + o); gll16(Al + a0, AsL + l0 + o);
      gll16(Bh + b0, BsH + l0 + o); gll16(Bl + b0, BsL + l0 + o);
      a0 += 32; b0 += 32;
    }
    size_t o = (size_t)cur * BUF;
    f16x8 ah[2], al_[2], bh[4], bl[4];
#pragma unroll
    for (int t = 0; t < 2; ++t) {
      ah[t]  = *(const f16x8*)(AsH + aoff[t] + o);
      al_[t] = *(const f16x8*)(AsL + aoff[t] + o);
    }
#pragma unroll
    for (int nt = 0; nt < 4; ++nt) {
      bh[nt] = *(const f16x8*)(BsH + boff[nt] + o);
      bl[nt] = *(const f16x8*)(BsL + boff[nt] + o);
    }
#pragma unroll
    for (int mt = 0; mt < 2; ++mt)
#pragma unroll
      for (int nt = 0; nt < 4; ++nt) {
        acc[mt][nt] = __builtin_amdgcn_mfma_f32_16x16x32_f16(
            ah[mt], bh[nt], acc[mt][nt], 0, 0, 0);
        acc[mt][nt] = __builtin_amdgcn_mfma_f32_16x16x32_f16(
            ah[mt], bl[nt], acc[mt][nt], 0, 0, 0);
        acc[mt][nt] = __builtin_amdgcn_mfma_f32_16x16x32_f16(
            al_[mt], bh[nt], acc[mt][nt], 0, 0, 0);
      }
  }

#pragma unroll
  for (int mt = 0; mt < 2; ++mt)
#pragma unroll
    for (int nt = 0; nt < 4; ++nt) {
      int c = col0 + wn * 64 + nt * 16 + mrow;
      float bv = bias ? bias[c] : 0.0f;
#pragma unroll
      for (int reg = 0; reg < 4; ++reg) {
        int r = row0 + wm * 32 + mt * 16 + quad * 4 + reg;
        C[(size_t)r * ldc + c] = acc[mt][nt][reg] + bv;
      }
    }
}

// ============ fused UVB GEMM: silu(n @ Wuv + buv) -> u/v (f16), base (f32) ==========
__global__ __launch_bounds__(512) void gemm_f16_uvb(
    const _Float16* __restrict__ A, int lda,
    const _Float16* __restrict__ Bt,           // Wuv^T block (1792 x 512)
    int c0, int nu,
    _Float16* __restrict__ ub, _Float16* __restrict__ vb, float* __restrict__ baseb,
    int CH, int K, const float* __restrict__ buv)
{
  const int BUF = 128 * 32;
  __shared__ _Float16 As[3 * BUF];
  __shared__ _Float16 Bs[3 * BUF];
  int bx = blockIdx.x, by = blockIdx.y;
  xcd_swizzle(bx, by);
  int tid = threadIdx.x;
  int lane = tid & 63, w = tid >> 6;        // 8 waves
  int wm = w >> 1, wn = w & 1;
  int row0 = by * 128;

  int x = bx;
  int xl, regbase, ldc_, is_base = 0;
  _Float16* dst16 = nullptr;
  if (x < nu)            { xl = x;          regbase = c0;        dst16 = ub; ldc_ = CH; }
  else if (x < 2 * nu)   { xl = x - nu;     regbase = 768 + c0;  dst16 = vb; ldc_ = CH; }
  else                   { xl = x - 2 * nu; regbase = 1536;      is_base = 1; ldc_ = 256; }
  int brow0 = regbase + xl * 128;
  int dcol0 = xl * 128;

  int m0 = tid >> 2;
  int k0e = (((tid & 3) - (m0 >> 1)) & 3) * 8;
  const _Float16* gA0 = A + (size_t)(row0 + m0) * lda + k0e;
  const _Float16* gB0 = Bt + (size_t)(brow0 + m0) * 512 + k0e;
  const _Float16* lA0 = As + (size_t)(w * 64) * 8;
  const _Float16* lB0 = Bs + (size_t)(w * 64) * 8;

  int mrow = lane & 15, quad = lane >> 4;
  const f16x8* aptr[2];
  const f16x8* bptr[4];
#pragma unroll
  for (int t = 0; t < 2; ++t) {
    int ml = wm * 32 + t * 16 + mrow;
    aptr[t] = (const f16x8*)(As + (size_t)(ml * 4 + ((quad + (ml >> 1)) & 3)) * 8);
  }
#pragma unroll
  for (int nt = 0; nt < 4; ++nt) {
    int nl = wn * 64 + nt * 16 + mrow;
    bptr[nt] = (const f16x8*)(Bs + (size_t)(nl * 4 + ((quad + (nl >> 1)) & 3)) * 8);
  }

  f32x4 acc[2][4] = {};

  int ntile = K >> 5;
  gll16(gA0, lA0); gll16(gB0, lB0);
  gA0 += 32; gB0 += 32;
  if (ntile > 1) {
    gll16(gA0, lA0 + BUF); gll16(gB0, lB0 + BUF);
    gA0 += 32; gB0 += 32;
  }

  int cur = 0;
  for (int t = 0; t < ntile; ++t) {
    if (t + 1 < ntile) asm volatile("s_waitcnt vmcnt(2)" ::: "memory");
    else               asm volatile("s_waitcnt vmcnt(0)" ::: "memory");
    __builtin_amdgcn_s_barrier();
    __builtin_amdgcn_sched_barrier(0);
    if (t + 2 < ntile) {
      int pf = cur + 2; if (pf >= 3) pf -= 3;
      gll16(gA0, lA0 + pf * BUF); gll16(gB0, lB0 + pf * BUF);
      gA0 += 32; gB0 += 32;
    }
    int fo = cur * (BUF / 8);
    f16x8 af[2], bfr[4];
#pragma unroll
    for (int tt = 0; tt < 2; ++tt) af[tt] = *(aptr[tt] + fo);
#pragma unroll
    for (int nt = 0; nt < 4; ++nt) bfr[nt] = *(bptr[nt] + fo);
#pragma unroll
    for (int mt = 0; mt < 2; ++mt)
#pragma unroll
      for (int nt = 0; nt < 4; ++nt)
        acc[mt][nt] = __builtin_amdgcn_mfma_f32_16x16x32_f16(
            af[mt], bfr[nt], acc[mt][nt], 0, 0, 0);
    cur = (cur == 2) ? 0 : cur + 1;
  }

#pragma unroll
  for (int mt = 0; mt < 2; ++mt) {
#pragma unroll
    for (int nt = 0; nt < 4; ++nt) {
      int lc = wn * 64 + nt * 16 + mrow;
      float bv = buv[brow0 + lc];
#pragma unroll
      for (int reg = 0; reg < 4; ++reg) {
        int r = row0 + wm * 32 + mt * 16 + quad * 4 + reg;
        float val = silu_f(acc[mt][nt][reg] + bv);
        if (is_base) baseb[(size_t)r * 256 + dcol0 + lc] = val;
        else         dst16[(size_t)r * ldc_ + dcol0 + lc] = (_Float16)val;
      }
    }
  }
}

// ============ fused attention: a = relu(qk^T/64)^2 in LDS, then t = (a@v)*u =========
// Round-6: nch=1 (single wg per bucket does ALL of phase B) -> phase A computed
// once instead of 3x. Phase B double-buffers vT in the dead qs/ks slabs ->
// ONE barrier per e0-iter (WAR audit: iter i+2's writes to slab p follow
// barrier(i+1); every thread's iter-i reads of slab p precede its barrier(i+1)).
__global__ __launch_bounds__(256) void attnapply_fused(
    const float* __restrict__ base, const float* __restrict__ gb,
    const float* __restrict__ bb, const _Float16* __restrict__ v,
    const _Float16* __restrict__ u, _Float16* __restrict__ t, int CH, int ech)
{
  __shared__ _Float16 smem[3 * 64 * 72];
  _Float16* qs = smem;
  _Float16* ks = smem + 64 * 72;
  _Float16* al = smem + 2 * 64 * 72;

  int bx = blockIdx.x, by = blockIdx.y;
  xcd_swizzle(bx, by);
  int g = by, tid = threadIdx.x;
  int e_lo = bx * ech, e_hi = e_lo + ech;
  int lane = tid & 63, w = tid >> 6;
  int mrow = lane & 15, quad = lane >> 4;
  int srow = tid >> 2, scol = (tid & 3) * 16;

  // ---- phase A: scores ----
  f32x4 acc[4] = {};
  for (int s0 = 0; s0 < 256; s0 += 64) {
    const float* bp = base + ((size_t)g * 64 + srow) * 256 + s0 + scol;
#pragma unroll
    for (int j4 = 0; j4 < 4; ++j4) {
      float4 xv = *(const float4*)(bp + j4 * 4);
      float xx[4] = {xv.x, xv.y, xv.z, xv.w};
#pragma unroll
      for (int j = 0; j < 4; ++j) {
        int s = s0 + scol + j4 * 4 + j;
        qs[srow * 72 + scol + j4 * 4 + j] = (_Float16)(xx[j] * gb[s] + bb[s]);
        ks[srow * 72 + scol + j4 * 4 + j] = (_Float16)(xx[j] * gb[256 + s] + bb[256 + s]);
      }
    }
    __syncthreads();
#pragma unroll
    for (int ks2 = 0; ks2 < 2; ++ks2) {
      f16x8 aq = *(const f16x8*)(qs + (w * 16 + mrow) * 72 + ks2 * 32 + quad * 8);
#pragma unroll
      for (int nt = 0; nt < 4; ++nt) {
        f16x8 bk = *(const f16x8*)(ks + (nt * 16 + mrow) * 72 + ks2 * 32 + quad * 8);
        acc[nt] = __builtin_amdgcn_mfma_f32_16x16x32_f16(aq, bk, acc[nt], 0, 0, 0);
      }
    }
    __syncthreads();
  }
#pragma unroll
  for (int nt = 0; nt < 4; ++nt)
#pragma unroll
    for (int reg = 0; reg < 4; ++reg) {
      float val = acc[nt][reg] * (1.0f / 64.0f);
      val = val > 0.0f ? val : 0.0f;
      val = val * val;
      al[(w * 16 + quad * 4 + reg) * 72 + nt * 16 + mrow] = (_Float16)val;
    }
  __syncthreads();

  // ---- phase B: t = (a @ v) * u on [e_lo, e_hi); vT alternates slabs 0/1 ----
  int p = 0;
  for (int e0 = e_lo; e0 < e_hi; e0 += 64, p ^= 1) {
    _Float16* vT = smem + p * 64 * 72;     // qs/ks are dead in phase B
    const _Float16* vp = v + ((size_t)g * 64 + srow) * CH + e0 + scol;
    f16x8 x0 = *(const f16x8*)vp;
    f16x8 x1 = *(const f16x8*)(vp + 8);
#pragma unroll
    for (int j = 0; j < 8; ++j) {
      vT[(scol + j) * 72 + srow] = x0[j];
      vT[(scol + 8 + j) * 72 + srow] = x1[j];
    }
    __syncthreads();
    f32x4 acc2[4] = {};
#pragma unroll
    for (int ks2 = 0; ks2 < 2; ++ks2) {
      f16x8 af = *(const f16x8*)(al + (w * 16 + mrow) * 72 + ks2 * 32 + quad * 8);
#pragma unroll
      for (int nt = 0; nt < 4; ++nt) {
        f16x8 bf = *(const f16x8*)(vT + (nt * 16 + mrow) * 72 + ks2 * 32 + quad * 8);
        acc2[nt] = __builtin_amdgcn_mfma_f32_16x16x32_f16(af, bf, acc2[nt], 0, 0, 0);
      }
    }
#pragma unroll
    for (int nt = 0; nt < 4; ++nt)
#pragma unroll
      for (int reg = 0; reg < 4; ++reg) {
        int row = w * 16 + quad * 4 + reg;
        int col = e0 + nt * 16 + mrow;
        size_t idx = ((size_t)g * 64 + row) * CH + col;
        t[idx] = (_Float16)(acc2[nt][reg] * (float)u[idx]);
      }
    // no trailing barrier: next iter writes the OTHER slab; the overwrite of
    // this slab happens only after the next iter's barrier.
  }
}

// ---------------- generic fp32 GEMM (fallback stage A + small tails) ----------------
__global__ __launch_bounds__(256) void gemm_f32(
    const float* __restrict__ A, int lda,
    const float* __restrict__ B, int ldb,
    float* __restrict__ C, int ldc,
    int M, int N, int K,
    const float* __restrict__ bias, int mode,
    const int* __restrict__ ids,
    const float* __restrict__ X,
    const float* __restrict__ alpha)
{
  __shared__ float As[16][68];
  __shared__ float Bs[16][68];
  int tid = threadIdx.x;
  int tx = tid & 15, ty = tid >> 4;
  int col0 = blockIdx.x * 64, row0 = blockIdx.y * 64;
  float acc[4][4] = {};
  int arow = tid >> 2;
  int ak   = (tid & 3) * 4;
  int bk   = tid >> 4;
  int bn   = (tid & 15) * 4;

  for (int kt = 0; kt < K; kt += 16) {
    float4 av = make_float4(0.f, 0.f, 0.f, 0.f);
    if (row0 + arow < M)
      av = *(const float4*)&A[(size_t)(row0 + arow) * lda + kt + ak];
    As[ak + 0][arow] = av.x; As[ak + 1][arow] = av.y;
    As[ak + 2][arow] = av.z; As[ak + 3][arow] = av.w;
    float4 bv = *(const float4*)&B[(size_t)(kt + bk) * ldb + col0 + bn];
    *(float4*)&Bs[bk][bn] = bv;
    __syncthreads();
#pragma unroll
    for (int k = 0; k < 16; ++k) {
      const float4 a4 = *(const float4*)&As[k][ty * 4];
      const float4 b4 = *(const float4*)&Bs[k][tx * 4];
      float a_[4] = {a4.x, a4.y, a4.z, a4.w};
      float b_[4] = {b4.x, b4.y, b4.z, b4.w};
#pragma unroll
      for (int i = 0; i < 4; ++i)
#pragma unroll
        for (int j = 0; j < 4; ++j)
          acc[i][j] = fmaf(a_[i], b_[j], acc[i][j]);
    }
    __syncthreads();
  }

#pragma unroll
  for (int i = 0; i < 4; ++i) {
    int r = row0 + ty * 4 + i;
    if (r >= M) continue;
#pragma unroll
    for (int j = 0; j < 4; ++j) {
      int c = col0 + tx * 4 + j;
      float val = acc[i][j] + (bias ? bias[c] : 0.0f);
      if (mode == OP_STORE) {
        C[(size_t)r * ldc + c] = val;
      } else if (mode == OP_SILU) {
        C[(size_t)r * ldc + c] = silu_f(val);
      } else if (mode == OP_RESID) {
        int hr = ids ? ids[r] : r;
        C[(size_t)hr * ldc + c] += val;
      } else { // OP_TR
        C[(size_t)r * ldc + c] = X[(size_t)r * ldc + c] + gelu_f(val) * alpha[0];
      }
    }
  }
}

// ---------------- weight transpose + cast ----------------
__global__ __launch_bounds__(256) void transpose_cast(
    const float* __restrict__ in, _Float16* __restrict__ out, int K, int N)
{
  in  += (size_t)blockIdx.z * K * N;
  out += (size_t)blockIdx.z * K * N;
  __shared__ float t[32][33];
  int k0 = blockIdx.y * 32, n0 = blockIdx.x * 32;
  int tx = threadIdx.x & 31, ty = threadIdx.x >> 5;
  for (int i = ty; i < 32; i += 8) {
    int k = k0 + i, n = n0 + tx;
    t[i][tx] = (k < K && n < N) ? in[(size_t)k * N + n] : 0.0f;
  }
  __syncthreads();
  for (int i = ty; i < 32; i += 8) {
    int n = n0 + i, k = k0 + tx;
    if (n < N && k < K) out[(size_t)n * K + k] = (_Float16)t[tx][i];
  }
}

__global__ __launch_bounds__(256) void transpose_split(
    const float* __restrict__ in, _Float16* __restrict__ hi,
    _Float16* __restrict__ lo, int K, int N)
{
  __shared__ float t[32][33];
  int k0 = blockIdx.y * 32, n0 = blockIdx.x * 32;
  int tx = threadIdx.x & 31, ty = threadIdx.x >> 5;
  for (int i = ty; i < 32; i += 8) {
    int k = k0 + i, n = n0 + tx;
    t[i][tx] = (k < K && n < N) ? in[(size_t)k * N + n] : 0.0f;
  }
  __syncthreads();
  for (int i = ty; i < 32; i += 8) {
    int n = n0 + i, k = k0 + tx;
    if (n < N && k < K) {
      float x = t[tx][i];
      _Float16 h = (_Float16)x;
      hi[(size_t)n * K + k] = h;
      lo[(size_t)n * K + k] = (_Float16)(x - (float)h);
    }
  }
}

__global__ __launch_bounds__(256) void split_f16_kernel(
    const float* __restrict__ in, _Float16* __restrict__ hi,
    _Float16* __restrict__ lo, int n)
{
  int i = blockIdx.x * 256 + threadIdx.x;
  if (i < n) {
    float x = in[i];
    _Float16 h = (_Float16)x;
    hi[i] = h;
    lo[i] = (_Float16)(x - (float)h);
  }
}

// ---------------- layernorm over 512 + optional gather/leaky/norm2-out ----------
// Round-6: shuffle-based reduction (6 shfl steps + one 4-entry LDS exchange,
// 1 barrier) replacing the 8-barrier 256-wide LDS tree.
template <typename OUT>
__global__ __launch_bounds__(256) void ln_kernel(
    const float* __restrict__ src, const int* __restrict__ ids,
    OUT* __restrict__ dst, const float* __restrict__ g,
    const float* __restrict__ b, float eps, int leaky,
    float* __restrict__ nrm2)
{
  int r = blockIdx.x;
  int sr = ids ? ids[r] : r;
  int tid = threadIdx.x;
  int lane = tid & 63, w = tid >> 6;
  float v0 = src[(size_t)sr * 512 + tid];
  float v1 = src[(size_t)sr * 512 + tid + 256];
  __shared__ float ws[4], ws2[4];
  float s = v0 + v1;
  float s2 = v0 * v0 + v1 * v1;
#pragma unroll
  for (int off = 32; off > 0; off >>= 1) {
    s  += __shfl_down(s, off, 64);
    s2 += __shfl_down(s2, off, 64);
  }
  if (lane == 0) { ws[w] = s; ws2[w] = s2; }
  __syncthreads();
  s  = ws[0] + ws[1] + ws[2] + ws[3];
  s2 = ws2[0] + ws2[1] + ws2[2] + ws2[3];
  float mean = s * (1.0f / 512.0f);
  float var  = s2 * (1.0f / 512.0f) - mean * mean;
  float rs = rsqrtf(var + eps);
  float o0 = (v0 - mean) * rs * g[tid] + b[tid];
  float o1 = (v1 - mean) * rs * g[tid + 256] + b[tid + 256];
  if (leaky) {
    o0 = o0 > 0.0f ? o0 : 0.1f * o0;
    o1 = o1 > 0.0f ? o1 : 0.1f * o1;
  }
  dst[(size_t)r * 512 + tid] = (OUT)o0;
  dst[(size_t)r * 512 + tid + 256] = (OUT)o1;
  if (nrm2) {
    float q = o0 * o0 + o1 * o1;
#pragma unroll
    for (int off = 32; off > 0; off >>= 1) q += __shfl_down(q, off, 64);
    __syncthreads();                 // all reads of ws done before reuse
    if (lane == 0) ws[w] = q;
    __syncthreads();
    if (tid == 0) nrm2[r] = ws[0] + ws[1] + ws[2] + ws[3];
  }
}

// ---------------- row gather: dst[r] = src[ids[r]] ----------------
__global__ __launch_bounds__(128) void permute_rows(
    const float* __restrict__ src, const int* __restrict__ ids,
    float* __restrict__ dst)
{
  int r = blockIdx.x, sr = ids[r];
  const float4* s = (const float4*)(src + (size_t)sr * 512);
  float4* d = (float4*)(dst + (size_t)r * 512);
  d[threadIdx.x] = s[threadIdx.x];
}

// ---------------- bitonic argsort of 4096 keys per sample ----------------
__global__ __launch_bounds__(1024) void sort_kernel(const float* __restrict__ norm2,
                                                    int* __restrict__ ids)
{
  __shared__ float key[4096];
  __shared__ int   val[4096];
  int s = blockIdx.x, tid = threadIdx.x;
  for (int i = tid; i < 4096; i += 1024) { key[i] = norm2[s * 4096 + i]; val[i] = i; }
  __syncthreads();
  for (int len = 2; len <= 4096; len <<= 1) {
    for (int j = len >> 1; j > 0; j >>= 1) {
      for (int t = tid; t < 2048; t += 1024) {
        int i1 = (t << 1) - (t & (j - 1));
        int i2 = i1 + j;
        bool up = ((i1 & len) == 0);
        float ka = key[i1], kb = key[i2];
        int va = val[i1], vb = val[i2];
        bool gt = (ka > kb) || (ka == kb && va > vb);
        if (gt == up) {
          key[i1] = kb; key[i2] = ka;
          val[i1] = vb; val[i2] = va;
        }
      }
      __syncthreads();
    }
  }
  for (int i = tid; i < 4096; i += 1024) ids[s * 4096 + i] = s * 4096 + val[i];
}

// ---------------- mean over groups of 64 rows (optional gather) ----------------
__global__ __launch_bounds__(256) void bucketmean_kernel(
    const float* __restrict__ src, const int* __restrict__ ids,
    float* __restrict__ dst)
{
  int g = blockIdx.x, tid = threadIdx.x;
  float s0 = 0.0f, s1 = 0.0f;
  for (int i = 0; i < 64; ++i) {
    int r = g * 64 + i;
    if (ids) r = ids[r];
    s0 += src[(size_t)r * 512 + tid];
    s1 += src[(size_t)r * 512 + tid + 256];
  }
  dst[(size_t)g * 512 + tid] = s0 * (1.0f / 64.0f);
  dst[(size_t)g * 512 + tid + 256] = s1 * (1.0f / 64.0f);
}

__global__ void avg_kernel(const float* __restrict__ a, const float* __restrict__ b,
                           float* __restrict__ o, int n)
{
  int i = blockIdx.x * 256 + threadIdx.x;
  if (i < n) o[i] = 0.5f * (a[i] + b[i]);
}

__global__ void out_kernel(const float* __restrict__ y, const float* __restrict__ W,
                           const float* __restrict__ b, float* __restrict__ out)
{
  int tid = threadIdx.x;
  if (tid < 8) {
    int s = tid >> 1, j = tid & 1;
    float acc = b[j];
    for (int d = 0; d < 512; ++d) acc += y[s * 512 + d] * W[d * 2 + j];
    out[s * 2 + j] = acc;
  }
}

extern "C" void kernel_launch(void* const* d_in, const int* in_sizes, int n_in,
                              void* d_out, int out_size, void* d_ws, size_t ws_size,
                              hipStream_t stream)
{
  const float* xs       = (const float*)d_in[0];
  const float* W_in     = (const float*)d_in[1];
  const float* b_in     = (const float*)d_in[2];
  const float* ln_in_g  = (const float*)d_in[3];
  const float* ln_in_b  = (const float*)d_in[4];
  const float* blk_ln_g = (const float*)d_in[5];
  const float* blk_ln_b = (const float*)d_in[6];
  const float* blk_Wuv  = (const float*)d_in[7];
  const float* blk_buv  = (const float*)d_in[8];
  const float* blk_gam  = (const float*)d_in[9];
  const float* blk_bet  = (const float*)d_in[10];
  const float* blk_Wo   = (const float*)d_in[11];
  const float* blk_bo   = (const float*)d_in[12];
  const float* tr_W     = (const float*)d_in[13];
  const float* tr_b     = (const float*)d_in[14];
  const float* tr_a     = (const float*)d_in[15];
  const float* tr2_W    = (const float*)d_in[16];
  const float* tr2_b    = (const float*)d_in[17];
  const float* tr2_a    = (const float*)d_in[18];
  const float* out_W    = (const float*)d_in[19];
  const float* out_b    = (const float*)d_in[20];
  float* outp = (float*)d_out;

  const size_t R1 = R1C;

  // ---- persistent carve ----
  char* wsb = (char*)d_ws;
  size_t off = 0;
  auto carve = [&](size_t bytes) {
    char* r = wsb + off;
    off = (off + bytes + 255) & ~(size_t)255;
    return (void*)r;
  };
  float* h      = (float*)carve(R1 * 512 * 4);   // unsorted residual (pre-permute)
  float* hslot  = (float*)carve(R1 * 512 * 4);   // sorted mode: hs; fallback: nb
  float* norm2b = (float*)carve(R1 * 4);
  int*   idsb   = (int*)carve(R1 * 4);
  float* gy     = (float*)carve((size_t)256 * 512 * 4);
  float* tl     = (float*)carve((size_t)256 * 512 * 4);
  float* gy2    = (float*)carve(4 * 512 * 4);
  float* ys0    = (float*)carve(4 * 512 * 4);
  float* ys1    = (float*)carve(4 * 512 * 4);
  float* yv     = (float*)carve(4 * 512 * 4);
  float* y2     = (float*)carve(4 * 512 * 4);
  _Float16* Wuvt = (_Float16*)carve((size_t)6 * 1792 * 512 * 2);
  _Float16* Wot  = (_Float16*)carve((size_t)6 * 512 * 768 * 2);
  size_t persistent = off;

  // ---- union sizing ----
  size_t stageA_sorted = 2 * R1 * 768 * 2 + 2 * (size_t)512 * 768 * 2 + R1 * 512 * 4 + 2048;
  size_t block768 = R1 * 256 * 4 + 3 * R1 * (size_t)768 * 2 + 2048;
  size_t un_sorted = stageA_sorted > block768 ? stageA_sorted : block768;
  bool sorted_mode = (persistent + un_sorted + 4096 <= ws_size);

  int CH = 768;
  bool splitA = true;
  if (!sorted_mode) {
    size_t stageA_fb = 2 * R1 * 768 * 2 + 2 * (size_t)512 * 768 * 2 + 1024;
    auto block_bytes = [&](size_t ch) {
      return R1 * 256 * 4 + 3 * R1 * ch * 2 + 2048;
    };
    CH = 0; splitA = false;
    const int cand[4] = {768, 384, 256, 128};
    for (int ci = 0; ci < 4; ++ci) {
      size_t bb2 = block_bytes(cand[ci]);
      size_t un2 = bb2 > stageA_fb ? bb2 : stageA_fb;
      if (persistent + un2 + 4096 <= ws_size) { CH = cand[ci]; splitA = true; break; }
    }
    if (!CH) {
      for (int ci = 0; ci < 4; ++ci)
        if (persistent + block_bytes(cand[ci]) + 4096 <= ws_size) { CH = cand[ci]; break; }
      if (!CH) CH = 128;
    }
  }
  int nu = CH / 128;
  int ech = CH;                       // round-6: one wg per bucket does all cols
  int nch = 1;

  char* un = wsb + ((persistent + 255) & ~(size_t)255);
  // stage-A overlay
  _Float16* xs_hi = (_Float16*)un;
  _Float16* xs_lo = xs_hi + R1 * 768;
  _Float16* Wt_hi = xs_lo + R1 * 768;
  _Float16* Wt_lo = Wt_hi + (size_t)512 * 768;
  float*    nbA   = sorted_mode ? (float*)(Wt_lo + (size_t)512 * 768) : hslot;
  // block overlay
  float*    baseb = (float*)un;
  _Float16* ub    = (_Float16*)(un + R1 * 256 * 4);
  _Float16* vb    = ub + R1 * (size_t)CH;
  _Float16* tb    = vb + R1 * (size_t)CH;
  _Float16* nbuf  = sorted_mode ? tb : (_Float16*)hslot;
  float* hres = sorted_mode ? hslot : h;
  const int* blkids = sorted_mode ? nullptr : idsb;

  dim3 blk(256);
  dim3 blk5(512);

  // ---- weight prep ----
  transpose_cast<<<dim3(56, 16, 6), blk, 0, stream>>>(blk_Wuv, Wuvt, 512, 1792);
  transpose_cast<<<dim3(16, 24, 6), blk, 0, stream>>>(blk_Wo, Wot, 768, 512);

  // ---- Stage A ----
  if (splitA) {
    split_f16_kernel<<<(int)(R1 * 768 / 256), blk, 0, stream>>>(xs, xs_hi, xs_lo,
                                                                (int)(R1 * 768));
    transpose_split<<<dim3(16, 24, 1), blk, 0, stream>>>(W_in, Wt_hi, Wt_lo, 768, 512);
    gemm_f16_split<<<dim3(4, 128), blk5, 0, stream>>>(xs_hi, xs_lo, 768,
        Wt_hi, Wt_lo, 768, nbA, 512, 768, b_in);
  } else {
    gemm_f32<<<dim3(8, 256), blk, 0, stream>>>(xs, 768, W_in, 512, nbA, 512,
        16384, 512, 768, b_in, OP_STORE, nullptr, nullptr, nullptr);
  }
  ln_kernel<float><<<16384, 256, 0, stream>>>(nbA, nullptr, h, ln_in_g, ln_in_b,
                                              1e-8f, 1, norm2b);
  sort_kernel<<<4, 1024, 0, stream>>>(norm2b, idsb);
  if (sorted_mode)
    permute_rows<<<16384, 128, 0, stream>>>(h, idsb, hres);

  // ---- Iteration 1: 6 subnet blocks over 256 buckets ----
  for (int b = 0; b < 6; ++b) {
    const _Float16* Wuv_t = Wuvt + (size_t)b * 1792 * 512;
    const float*    buv   = blk_buv + b * 1792;
    const _Float16* Wo_t  = Wot + (size_t)b * 512 * 768;
    ln_kernel<_Float16><<<16384, 256, 0, stream>>>(hres, blkids, nbuf,
        blk_ln_g + b * 512, blk_ln_b + b * 512, 1e-5f, 0, nullptr);
    for (int c0 = 0; c0 < 768; c0 += CH) {
      int incl = (c0 == 0) ? 2 : 0;
      gemm_f16_uvb<<<dim3(2 * nu + incl, 128), blk5, 0, stream>>>(nbuf, 512, Wuv_t,
          c0, nu, ub, vb, baseb, CH, 512, buv);
      attnapply_fused<<<dim3(nch, 256), blk, 0, stream>>>(baseb, blk_gam + b * 512,
          blk_bet + b * 512, vb, ub, tb, CH, ech);
      const float* bo = (c0 + CH == 768) ? (blk_bo + b * 512) : nullptr;
      gemm_f16<<<dim3(4, 128), blk5, 0, stream>>>(tb, CH, Wo_t + c0, 768,
          hres, 512, CH, bo, OP_RESID, blkids);
    }
  }
  bucketmean_kernel<<<256, 256, 0, stream>>>(hres, blkids, gy);

  // ---- ys0 = mean_buckets(tr_layer(gy)) ----
  gemm_f32<<<dim3(8, 4), blk, 0, stream>>>(gy, 512, tr_W, 512, tl, 512,
      256, 512, 512, tr_b, OP_TR, nullptr, gy, tr_a);
  bucketmean_kernel<<<4, 256, 0, stream>>>(tl, nullptr, ys0);

  // ---- Iteration 2: 64 rows/sample == 1 bucket; sort permutation cancels ----
  for (int b = 0; b < 6; ++b) {
    const _Float16* Wuv_t = Wuvt + (size_t)b * 1792 * 512;
    const float*    buv   = blk_buv + b * 1792;
    const _Float16* Wo_t  = Wot + (size_t)b * 512 * 768;
    ln_kernel<_Float16><<<256, 256, 0, stream>>>(gy, nullptr, nbuf, blk_ln_g + b * 512,
                                                 blk_ln_b + b * 512, 1e-5f, 0, nullptr);
    for (int c0 = 0; c0 < 768; c0 += CH) {
      int incl = (c0 == 0) ? 2 : 0;
      gemm_f16_uvb<<<dim3(2 * nu + incl, 2), blk5, 0, stream>>>(nbuf, 512, Wuv_t,
          c0, nu, ub, vb, baseb, CH, 512, buv);
      attnapply_fused<<<dim3(nch, 4), blk, 0, stream>>>(baseb, blk_gam + b * 512,
          blk_bet + b * 512, vb, ub, tb, CH, ech);
      const float* bo = (c0 + CH == 768) ? (blk_bo + b * 512) : nullptr;
      gemm_f16<<<dim3(4, 2), blk5, 0, stream>>>(tb, CH, Wo_t + c0, 768,
          gy, 512, CH, bo, OP_RESID, nullptr);
    }
  }
  bucketmean_kernel<<<4, 256, 0, stream>>>(gy, nullptr, gy2);

  // ---- tails ----
  gemm_f32<<<dim3(8, 1), blk, 0, stream>>>(gy2, 512, tr_W, 512, ys1, 512,
      4, 512, 512, tr_b, OP_TR, nullptr, gy2, tr_a);
  avg_kernel<<<8, 256, 0, stream>>>(ys0, ys1, yv, 2048);
  gemm_f32<<<dim3(8, 1), blk, 0, stream>>>(yv, 512, tr2_W, 512, y2, 512,
      4, 512, 512, tr2_b, OP_TR, nullptr, yv, tr2_a);
  out_kernel<<<1, 64, 0, stream>>>(y2, out_W, out_b, outp);
}